// Round 4
// baseline (180.980 us; speedup 1.0000x reference)
//
#include <hip/hip_runtime.h>
#include <stdint.h>

#define GK 2048
#define GN 2048
#define GM 8192  // tokens = 4 * 2048

#define NVX (GM * (unsigned)GK / 4)   // 4,194,304 float4 in x
#define NVW (GN * (unsigned)GK / 4)   // 1,048,576 float4 in w

#define XBLK 1024  // absmax x-blocks: 4194304/(1024*256) = 16 iters exactly
#define WBLK 256   // absmax w-blocks: 1048576/(256*256)  = 16 iters exactly
#define QXBLK 4096 // quant x-blocks: 4 float4/thread exactly
#define QWBLK 1024 // quant w-blocks

typedef int i32x4  __attribute__((ext_vector_type(4)));
typedef int i32x16 __attribute__((ext_vector_type(16)));

__device__ __forceinline__ float amax4(float4 v) {
    return fmaxf(fmaxf(fabsf(v.x), fabsf(v.y)), fmaxf(fabsf(v.z), fabsf(v.w)));
}

// ---------------------------------------------------------------------------
// Stage 1: per-block absmax partials (no atomics; ILP-4 loads, no inner branch)
// blocks [0,XBLK): x ; [XBLK, XBLK+WBLK): w. partial[blockIdx] <- block max.
// ---------------------------------------------------------------------------
__global__ __launch_bounds__(256) void absmax_kernel(
    const float4* __restrict__ xv, const float4* __restrict__ wv,
    float* __restrict__ partial)
{
    const bool isx = blockIdx.x < XBLK;
    const float4* __restrict__ src = isx ? xv : wv;
    const unsigned n      = isx ? NVX : NVW;
    const unsigned b0     = isx ? blockIdx.x : blockIdx.x - XBLK;
    const unsigned stride = (isx ? XBLK : WBLK) * 256u;

    unsigned i = b0 * 256u + threadIdx.x;
    float m = 0.f;
    for (; i + 3u * stride < n; i += 4u * stride) {
        float4 a = src[i];
        float4 b = src[i + stride];
        float4 c = src[i + 2u * stride];
        float4 d = src[i + 3u * stride];
        m = fmaxf(m, fmaxf(fmaxf(amax4(a), amax4(b)),
                           fmaxf(amax4(c), amax4(d))));
    }
    for (; i < n; i += stride) m = fmaxf(m, amax4(src[i]));  // safety tail

    #pragma unroll
    for (int off = 32; off > 0; off >>= 1)
        m = fmaxf(m, __shfl_xor(m, off, 64));

    __shared__ float sm[4];
    const int wid = threadIdx.x >> 6;
    if ((threadIdx.x & 63) == 0) sm[wid] = m;
    __syncthreads();
    if (threadIdx.x == 0)
        partial[blockIdx.x] = fmaxf(fmaxf(sm[0], sm[1]), fmaxf(sm[2], sm[3]));
}

// ---------------------------------------------------------------------------
// Stage 1b: single-block reduce of 1280 partials -> scales{sx, sw, sx*sw}
// Numerics identical to reference: scale = absmax / 127.0f (IEEE fp32 div).
// ---------------------------------------------------------------------------
__global__ __launch_bounds__(256) void scale_kernel(
    const float* __restrict__ partial, float* __restrict__ scales)
{
    const int t = threadIdx.x;
    float mx = fmaxf(fmaxf(partial[t], partial[t + 256]),
                     fmaxf(partial[t + 512], partial[t + 768]));  // [0,1024)
    float mw = partial[XBLK + t];                                  // [1024,1280)
    #pragma unroll
    for (int off = 32; off > 0; off >>= 1) {
        mx = fmaxf(mx, __shfl_xor(mx, off, 64));
        mw = fmaxf(mw, __shfl_xor(mw, off, 64));
    }
    __shared__ float smx[4], smw[4];
    const int wid = t >> 6;
    if ((t & 63) == 0) { smx[wid] = mx; smw[wid] = mw; }
    __syncthreads();
    if (t == 0) {
        float ax = fmaxf(fmaxf(smx[0], smx[1]), fmaxf(smx[2], smx[3]));
        float aw = fmaxf(fmaxf(smw[0], smw[1]), fmaxf(smw[2], smw[3]));
        float sx = ax / 127.0f;
        float sw = aw / 127.0f;
        scales[0] = sx;
        scales[1] = sw;
        scales[2] = sx * sw;
    }
}

// ---------------------------------------------------------------------------
// Stage 2: quantize. Bit-exact vs reference: q = rintf(v / scale) (half-even,
// IEEE div), clip [-128,127], cast. ILP-4, unit-stride loads AND stores.
// ---------------------------------------------------------------------------
__device__ __forceinline__ signed char quant1(float v, float s) {
    float r = rintf(v / s);
    r = fminf(fmaxf(r, -128.f), 127.f);
    return (signed char)(int)r;
}

__device__ __forceinline__ char4 quantv(float4 v, float s) {
    char4 q;
    q.x = quant1(v.x, s); q.y = quant1(v.y, s);
    q.z = quant1(v.z, s); q.w = quant1(v.w, s);
    return q;
}

__global__ __launch_bounds__(256) void quant_kernel(
    const float4* __restrict__ xv, const float4* __restrict__ wv,
    const float* __restrict__ scales,
    char4* __restrict__ xq, char4* __restrict__ wq)
{
    const bool isx = blockIdx.x < QXBLK;
    const float s = isx ? scales[0] : scales[1];
    const float4* __restrict__ src = isx ? xv : wv;
    char4* __restrict__ dst        = isx ? xq : wq;
    const unsigned b0     = isx ? blockIdx.x : blockIdx.x - QXBLK;
    const unsigned stride = (isx ? QXBLK : QWBLK) * 256u;
    const unsigned t      = b0 * 256u + threadIdx.x;

    float4 a = src[t];
    float4 b = src[t + stride];
    float4 c = src[t + 2u * stride];
    float4 d = src[t + 3u * stride];
    dst[t]               = quantv(a, s);
    dst[t + stride]      = quantv(b, s);
    dst[t + 2u * stride] = quantv(c, s);
    dst[t + 3u * stride] = quantv(d, s);
}

// ---------------------------------------------------------------------------
// Stage 3: int8 GEMM, 128x128 tile, BK=128, 4 waves (2x2), each wave 64x64 =
// 2x2 fragments of mfma_i32_32x32x32_i8 (half the MFMA issues of 16x16x64).
// global_load_lds width-16 with pre-swizzled source, swizzled ds_read_b128,
// T1 bijective XCD swizzle (1024 blocks % 8 == 0), fused dequant+bias.
// A = xq [M,K] row-major; B = wq [N,K] row-major (weight is [out,in] = B^T).
//
// Fragment layouts (i8 32x32x32, by the same analogy verified for 16x16x64):
//   A/B: row = lane&31, 16B k-chunk at k = ks*32 + (lane>>5)*16
//   C/D (m74/m101, dtype-independent): col = lane&31,
//        row = (reg&3) + 8*(reg>>2) + 4*(lane>>5)
// ---------------------------------------------------------------------------
__global__ __launch_bounds__(256) void gemm_kernel(
    const signed char* __restrict__ Aq,
    const signed char* __restrict__ Bq,
    const float* __restrict__ bias,
    const float* __restrict__ scales,
    float* __restrict__ out)
{
    __shared__ signed char sA[128 * 128];
    __shared__ signed char sB[128 * 128];

    const int tid  = threadIdx.x;
    const int lane = tid & 63;
    const int wid  = tid >> 6;
    const int wr   = wid >> 1;      // wave row 0..1 (64-row strip)
    const int wc   = wid & 1;       // wave col 0..1 (64-col strip)

    // T1: XCD-aware swizzle. Dispatch round-robins XCD = blockIdx.x % 8; give
    // each XCD a contiguous chunk of 128 tiles (8 bm-rows x 16 bn) so A panels
    // (8 x 256KB = 2MB) and B (4MB) stay L2-resident per XCD.
    const int wgid = ((blockIdx.x & 7) << 7) | (blockIdx.x >> 3);
    const int bn   = wgid & 15;     // GN/128 = 16
    const int bm   = wgid >> 4;

    // staging coords: 256 threads x 16B = 4096B per issue (32 rows x 128B)
    const int srow  = tid >> 3;     // 0..31
    const int sslot = tid & 7;      // 0..7 (16B slot within 128B row)

    i32x16 acc[2][2] = {};

    const long Abase = (long)bm * 128 * GK;
    const long Bbase = (long)bn * 128 * GK;

    for (int kt = 0; kt < GK; kt += 128) {
        #pragma unroll
        for (int j = 0; j < 4; ++j) {
            const int row  = j * 32 + srow;
            const int slot = sslot ^ (row & 7);       // pre-swizzled source
            const signed char* src = Aq + Abase + (long)row * GK + kt + slot * 16;
            __builtin_amdgcn_global_load_lds(
                (const __attribute__((address_space(1))) void*)src,
                (__attribute__((address_space(3))) void*)(sA + j * 4096 + wid * 1024),
                16, 0, 0);
        }
        #pragma unroll
        for (int j = 0; j < 4; ++j) {
            const int row  = j * 32 + srow;
            const int slot = sslot ^ (row & 7);
            const signed char* src = Bq + Bbase + (long)row * GK + kt + slot * 16;
            __builtin_amdgcn_global_load_lds(
                (const __attribute__((address_space(1))) void*)src,
                (__attribute__((address_space(3))) void*)(sB + j * 4096 + wid * 1024),
                16, 0, 0);
        }
        __syncthreads();   // drains vmcnt before barrier (compiler-inserted)

        #pragma unroll
        for (int ks = 0; ks < 4; ++ks) {              // K=32 slices of BK=128
            const int sl = ks * 2 + (lane >> 5);      // 16B slot 0..7
            i32x4 af[2], bf[2];
            #pragma unroll
            for (int m = 0; m < 2; ++m) {
                const int row = wr * 64 + m * 32 + (lane & 31);
                af[m] = *(const i32x4*)(sA + row * 128 + ((sl ^ (row & 7)) << 4));
            }
            #pragma unroll
            for (int n = 0; n < 2; ++n) {
                const int row = wc * 64 + n * 32 + (lane & 31);
                bf[n] = *(const i32x4*)(sB + row * 128 + ((sl ^ (row & 7)) << 4));
            }
            #pragma unroll
            for (int m = 0; m < 2; ++m)
                #pragma unroll
                for (int n = 0; n < 2; ++n)
                    acc[m][n] = __builtin_amdgcn_mfma_i32_32x32x32_i8(
                        af[m], bf[n], acc[m][n], 0, 0, 0);
        }
        __syncthreads();
    }

    // Epilogue: dequant + bias.
    const float s = scales[2];
    const int orow0 = bm * 128 + wr * 64 + 4 * (lane >> 5);
    const int ocol0 = bn * 128 + wc * 64 + (lane & 31);
    #pragma unroll
    for (int n = 0; n < 2; ++n) {
        const int col = ocol0 + n * 32;
        const float bv = bias[col];
        #pragma unroll
        for (int m = 0; m < 2; ++m) {
            #pragma unroll
            for (int r = 0; r < 16; ++r) {
                const int row = orow0 + m * 32 + (r & 3) + 8 * (r >> 2);
                out[(long)row * GN + col] = (float)acc[m][n][r] * s + bv;
            }
        }
    }
}

// ---------------------------------------------------------------------------
extern "C" void kernel_launch(void* const* d_in, const int* in_sizes, int n_in,
                              void* d_out, int out_size, void* d_ws, size_t ws_size,
                              hipStream_t stream) {
    const float* x    = (const float*)d_in[0];
    const float* w    = (const float*)d_in[1];
    const float* bias = (const float*)d_in[2];
    float* out = (float*)d_out;

    // ws layout: [0,16): scales {sx, sw, sx*sw}; [16, 16+1280*4): partials;
    // [8192, +16M): xq; then wq (4M). Every slot written before read.
    const size_t need = 8192 + (size_t)GM * GK + (size_t)GN * GK;
    if (ws_size < need) return;  // clean bail -> validation failure, not a crash

    float* scales    = (float*)d_ws;
    float* partial   = (float*)d_ws + 4;
    signed char* xq  = (signed char*)d_ws + 8192;
    signed char* wq  = xq + (size_t)GM * GK;

    absmax_kernel<<<XBLK + WBLK, 256, 0, stream>>>(
        (const float4*)x, (const float4*)w, partial);
    scale_kernel<<<1, 256, 0, stream>>>(partial, scales);
    quant_kernel<<<QXBLK + QWBLK, 256, 0, stream>>>(
        (const float4*)x, (const float4*)w, scales, (char4*)xq, (char4*)wq);
    gemm_kernel<<<(GM / 128) * (GN / 128), 256, 0, stream>>>(
        xq, wq, bias, scales, out);
}

// Round 5
// 174.953 us; speedup vs baseline: 1.0344x; 1.0344x over previous
//
#include <hip/hip_runtime.h>
#include <stdint.h>

#define GK 2048
#define GN 2048
#define GM 8192  // tokens = 4 * 2048

#define NVX (GM * (unsigned)GK / 4)   // 4,194,304 float4 in x
#define NVW (GN * (unsigned)GK / 4)   // 1,048,576 float4 in w

#define XBLK 1024  // absmax x-blocks: 16 iters exactly
#define WBLK 256   // absmax w-blocks: 16 iters exactly
#define QXBLK 4096 // quant x-blocks: 4 float4/thread exactly
#define QWBLK 1024 // quant w-blocks
#define NT (GK / 128)  // 16 K-tiles

typedef int i32x4 __attribute__((ext_vector_type(4)));

__device__ __forceinline__ float amax4(float4 v) {
    return fmaxf(fmaxf(fabsf(v.x), fabsf(v.y)), fmaxf(fabsf(v.z), fabsf(v.w)));
}

// ---------------------------------------------------------------------------
// Stage 1: per-block absmax partials (ILP-4, no atomics, no inner branch)
// ---------------------------------------------------------------------------
__global__ __launch_bounds__(256) void absmax_kernel(
    const float4* __restrict__ xv, const float4* __restrict__ wv,
    float* __restrict__ partial)
{
    const bool isx = blockIdx.x < XBLK;
    const float4* __restrict__ src = isx ? xv : wv;
    const unsigned n      = isx ? NVX : NVW;
    const unsigned b0     = isx ? blockIdx.x : blockIdx.x - XBLK;
    const unsigned stride = (isx ? XBLK : WBLK) * 256u;

    unsigned i = b0 * 256u + threadIdx.x;
    float m = 0.f;
    for (; i + 3u * stride < n; i += 4u * stride) {
        float4 a = src[i];
        float4 b = src[i + stride];
        float4 c = src[i + 2u * stride];
        float4 d = src[i + 3u * stride];
        m = fmaxf(m, fmaxf(fmaxf(amax4(a), amax4(b)),
                           fmaxf(amax4(c), amax4(d))));
    }
    for (; i < n; i += stride) m = fmaxf(m, amax4(src[i]));

    #pragma unroll
    for (int off = 32; off > 0; off >>= 1)
        m = fmaxf(m, __shfl_xor(m, off, 64));

    __shared__ float sm[4];
    const int wid = threadIdx.x >> 6;
    if ((threadIdx.x & 63) == 0) sm[wid] = m;
    __syncthreads();
    if (threadIdx.x == 0)
        partial[blockIdx.x] = fmaxf(fmaxf(sm[0], sm[1]), fmaxf(sm[2], sm[3]));
}

// ---------------------------------------------------------------------------
// Block-local reduce of the 1280 partials (x: [0,1024), w: [1024,1280)).
// Every consumer block redoes this (~5KB L2-hot) -> no scale kernel, no sync.
// First 256 threads participate; result broadcast via LDS.
// ---------------------------------------------------------------------------
__device__ __forceinline__ void reduce_scales(const float* __restrict__ partial,
                                              int tid, float* ax_out, float* aw_out)
{
    __shared__ float smx[4], smw[4];
    float mx = 0.f, mw = 0.f;
    if (tid < 256) {
        mx = fmaxf(fmaxf(partial[tid], partial[tid + 256]),
                   fmaxf(partial[tid + 512], partial[tid + 768]));
        mw = partial[1024 + tid];
        #pragma unroll
        for (int off = 32; off > 0; off >>= 1) {
            mx = fmaxf(mx, __shfl_xor(mx, off, 64));
            mw = fmaxf(mw, __shfl_xor(mw, off, 64));
        }
        if ((tid & 63) == 0) { smx[tid >> 6] = mx; smw[tid >> 6] = mw; }
    }
    __syncthreads();
    *ax_out = fmaxf(fmaxf(smx[0], smx[1]), fmaxf(smx[2], smx[3]));
    *aw_out = fmaxf(fmaxf(smw[0], smw[1]), fmaxf(smw[2], smw[3]));
}

// ---------------------------------------------------------------------------
// Stage 2: quantize. Bit-exact vs reference: q = rintf(v / (absmax/127)),
// half-even, IEEE div, clip, cast. ILP-4, unit-stride loads and stores.
// ---------------------------------------------------------------------------
__device__ __forceinline__ signed char quant1(float v, float s) {
    float r = rintf(v / s);
    r = fminf(fmaxf(r, -128.f), 127.f);
    return (signed char)(int)r;
}

__device__ __forceinline__ char4 quantv(float4 v, float s) {
    char4 q;
    q.x = quant1(v.x, s); q.y = quant1(v.y, s);
    q.z = quant1(v.z, s); q.w = quant1(v.w, s);
    return q;
}

__global__ __launch_bounds__(256) void quant_kernel(
    const float4* __restrict__ xv, const float4* __restrict__ wv,
    const float* __restrict__ partial,
    char4* __restrict__ xq, char4* __restrict__ wq)
{
    float ax, aw;
    reduce_scales(partial, threadIdx.x, &ax, &aw);

    const bool isx = blockIdx.x < QXBLK;
    const float s = (isx ? ax : aw) / 127.0f;
    const float4* __restrict__ src = isx ? xv : wv;
    char4* __restrict__ dst        = isx ? xq : wq;
    const unsigned b0     = isx ? blockIdx.x : blockIdx.x - QXBLK;
    const unsigned stride = (isx ? QXBLK : QWBLK) * 256u;
    const unsigned t      = b0 * 256u + threadIdx.x;

    float4 a = src[t];
    float4 b = src[t + stride];
    float4 c = src[t + 2u * stride];
    float4 d = src[t + 3u * stride];
    dst[t]               = quantv(a, s);
    dst[t + stride]      = quantv(b, s);
    dst[t + 2u * stride] = quantv(c, s);
    dst[t + 3u * stride] = quantv(d, s);
}

// ---------------------------------------------------------------------------
// Stage 3: int8 GEMM — 256x256 tile, BK=128 (128B rows), 8 waves (2M x 4N),
// 8-phase-style schedule (T3+T4+T5): 4 phases/K-tile, raw s_barrier (no vmcnt
// drain), next-tile staged in phases 0-1, ONE s_waitcnt vmcnt(0) per K-tile
// (>=2 phases after last issue -> latency hidden), setprio around MFMA.
// LDS: 2 x (A 32KB + B 32KB) = 128KB double buffer, XOR swizzle byte^=(row&7)<<4
// via pre-swizzled global source (R3-proven conflict-free with 16x16x64 reads).
// A = xq [M,K] rm; B = wq [N,K] rm (weight [out,in] = B^T).
// ---------------------------------------------------------------------------
__global__ __launch_bounds__(512, 2) void gemm_kernel(
    const signed char* __restrict__ Aq,
    const signed char* __restrict__ Bq,
    const float* __restrict__ bias,
    const float* __restrict__ partial,
    float* __restrict__ out)
{
    __shared__ signed char lds[131072];   // [2 bufs][A 32KB | B 32KB]

    const int tid  = threadIdx.x;
    const int lane = tid & 63;
    const int wid  = tid >> 6;       // 0..7
    const int wr   = wid >> 2;       // 0..1  -> M rows [wr*128, +128)
    const int wc   = wid & 3;        // 0..3  -> N cols [wc*64, +64)

    // T1 bijective XCD swizzle: 256 blocks, 8 XCDs, 32 consecutive wgids/XCD
    const int wgid = ((blockIdx.x & 7) << 5) | (blockIdx.x >> 3);
    const int bn   = wgid & 7;       // GN/256 = 8
    const int bm   = wgid >> 3;      // GM/256 = 32

    // scale product for epilogue (matches reference op order exactly)
    float ax, aw;
    reduce_scales(partial, tid, &ax, &aw);
    const float s = (ax / 127.0f) * (aw / 127.0f);

    // ---- staging constants: 8 issues/tile/thread (A:4, B:4), 16B each ----
    // issue he = h*2+e: LDS row = h*128 + e*64 + (tid>>3), slot = tid&7;
    // pre-swizzled source slot = (tid&7) ^ (row&7), row&7 = (tid>>3)&7.
    const int srcslot = (tid & 7) ^ ((tid >> 3) & 7);
    const signed char* aSrc[4]; const signed char* bSrc[4];
    int aDst[4], bDst[4];
    #pragma unroll
    for (int he = 0; he < 4; ++he) {
        const int h = he >> 1, e = he & 1;
        const int r = h * 128 + e * 64 + (tid >> 3);
        aSrc[he] = Aq + (long)(bm * 256 + r) * GK + srcslot * 16;
        bSrc[he] = Bq + (long)(bn * 256 + r) * GK + srcslot * 16;
        aDst[he] = h * 16384 + e * 8192 + tid * 16;            // within A region
        bDst[he] = 32768 + h * 16384 + e * 8192 + tid * 16;    // within B region
    }

    // ---- ds_read constants: frag row = base + 16*idx + (lane&15) ----
    const int lcol = lane & 15;
    const int g0   = lane >> 4;          // k-subslot 0..3
    const int r7   = lcol & 7;           // row&7 for every fragment row
    int aOff[8], bOff[4];
    #pragma unroll
    for (int mf = 0; mf < 8; ++mf) aOff[mf] = (wr * 128 + mf * 16 + lcol) * 128;
    #pragma unroll
    for (int n = 0; n < 4; ++n)    bOff[n] = 32768 + (wc * 64 + n * 16 + lcol) * 128;

    i32x4 acc[8][4] = {};

    // ---- prologue: stage tile 0 into buf 0, drain, publish scales ----
    #pragma unroll
    for (int he = 0; he < 4; ++he) {
        __builtin_amdgcn_global_load_lds(
            (const __attribute__((address_space(1))) void*)aSrc[he],
            (__attribute__((address_space(3))) void*)(lds + aDst[he]), 16, 0, 0);
        __builtin_amdgcn_global_load_lds(
            (const __attribute__((address_space(1))) void*)bSrc[he],
            (__attribute__((address_space(3))) void*)(lds + bDst[he]), 16, 0, 0);
    }
    __syncthreads();   // drains vmcnt(0) + barrier: tile 0 resident

    // ---- K loop: 16 tiles x 4 phases ----
    for (int t = 0; t < NT; ++t) {
        const signed char* buf = lds + (t & 1) * 65536;
        signed char* nbuf      = lds + ((t & 1) ^ 1) * 65536;
        const long knext = (long)(t + 1) * 128;
        i32x4 bf[4];

        #pragma unroll
        for (int ph = 0; ph < 4; ++ph) {
            const int mq = ph & 1, ks = ph >> 1;
            const int sw = ((ks * 4 + g0) ^ r7) << 4;   // swizzled 16B slot

            if ((ph & 1) == 0) {                        // ph 0,2: B frags for ks
                #pragma unroll
                for (int n = 0; n < 4; ++n)
                    bf[n] = *(const i32x4*)(buf + bOff[n] + sw);
            }
            i32x4 af[4];
            #pragma unroll
            for (int m = 0; m < 4; ++m)
                af[m] = *(const i32x4*)(buf + aOff[mq * 4 + m] + sw);

            if (ph == 0 && t + 1 < NT) {                // stage next A
                #pragma unroll
                for (int he = 0; he < 4; ++he)
                    __builtin_amdgcn_global_load_lds(
                        (const __attribute__((address_space(1))) void*)(aSrc[he] + knext),
                        (__attribute__((address_space(3))) void*)(nbuf + aDst[he]), 16, 0, 0);
            }
            if (ph == 1 && t + 1 < NT) {                // stage next B
                #pragma unroll
                for (int he = 0; he < 4; ++he)
                    __builtin_amdgcn_global_load_lds(
                        (const __attribute__((address_space(1))) void*)(bSrc[he] + knext),
                        (__attribute__((address_space(3))) void*)(nbuf + bDst[he]), 16, 0, 0);
            }

            __builtin_amdgcn_s_barrier();               // align waves (raw, no drain)
            __builtin_amdgcn_s_setprio(1);
            #pragma unroll
            for (int m = 0; m < 4; ++m)
                #pragma unroll
                for (int n = 0; n < 4; ++n)
                    acc[mq * 4 + m][n] = __builtin_amdgcn_mfma_i32_16x16x64_i8(
                        af[m], bf[n], acc[mq * 4 + m][n], 0, 0, 0);
            __builtin_amdgcn_s_setprio(0);

            if (ph == 3 && t + 1 < NT) {
                // my 8 stage-issues (>=2 phases old) must be in LDS before
                // anyone reads nbuf next tile: vmcnt(0) BEFORE the barrier.
                asm volatile("s_waitcnt vmcnt(0)" ::: "memory");
                __builtin_amdgcn_sched_barrier(0);
            }
            __builtin_amdgcn_s_barrier();
        }
    }

    // ---- epilogue: dequant + bias. C/D: col=lane&15, row=(lane>>4)*4+reg ----
    const int orow0 = bm * 256 + wr * 128 + (lane >> 4) * 4;
    const int ocol0 = bn * 256 + wc * 64 + lcol;
    #pragma unroll
    for (int n = 0; n < 4; ++n) {
        const int col = ocol0 + n * 16;
        const float bv = bias[col];
        #pragma unroll
        for (int mf = 0; mf < 8; ++mf) {
            const int row = orow0 + mf * 16;
            #pragma unroll
            for (int i = 0; i < 4; ++i)
                out[(long)(row + i) * GN + col] = (float)acc[mf][n][i] * s + bv;
        }
    }
}

// ---------------------------------------------------------------------------
extern "C" void kernel_launch(void* const* d_in, const int* in_sizes, int n_in,
                              void* d_out, int out_size, void* d_ws, size_t ws_size,
                              hipStream_t stream) {
    const float* x    = (const float*)d_in[0];
    const float* w    = (const float*)d_in[1];
    const float* bias = (const float*)d_in[2];
    float* out = (float*)d_out;

    // ws: [16, 16+1280*4): partials; [8192, +16M): xq; then wq (4M).
    const size_t need = 8192 + (size_t)GM * GK + (size_t)GN * GK;
    if (ws_size < need) return;

    float* partial   = (float*)d_ws + 4;
    signed char* xq  = (signed char*)d_ws + 8192;
    signed char* wq  = xq + (size_t)GM * GK;

    absmax_kernel<<<XBLK + WBLK, 256, 0, stream>>>(
        (const float4*)x, (const float4*)w, partial);
    quant_kernel<<<QXBLK + QWBLK, 256, 0, stream>>>(
        (const float4*)x, (const float4*)w, partial, (char4*)xq, (char4*)wq);
    gemm_kernel<<<(GM / 256) * (GN / 256), 512, 0, stream>>>(
        xq, wq, bias, partial, out);
}